// Round 5
// baseline (101.835 us; speedup 1.0000x reference)
//
#include <hip/hip_runtime.h>
#include <math.h>

#define N_SAMP 65536
#define DIM    512
#define NCLS   64
#define KSEL   64

// workspace layout (bytes)
#define OFF_COUNTS   0u          // 64 i32
#define OFF_CSUM     256u        // 64*512 f32 -> ends 131328
#define OFF_CENTERS  131328u     // cenb: 64*512 bf16 -> ends 196864
#define OFF_C2       196864u     // 64 f32 -> 197120
#define OFF_MEANS    197120u     // 128 f32 (pos[0..63], neg[64..127]) -> 197632
#define OFF_DONE     197632u     // 1 u32 (pad to 198144)
#define OFF_DIST     198144u     // 64*65536 f32

typedef __attribute__((ext_vector_type(8))) short bf16x8;
typedef __attribute__((ext_vector_type(4))) float f32x4;

__device__ __forceinline__ unsigned short f2bf_rne(float f) {
  const unsigned u = __float_as_uint(f);
  return (unsigned short)((u + 0x7FFFu + ((u >> 16) & 1u)) >> 16);
}

// ---------------------------------------------------------------- init
__global__ __launch_bounds__(256) void k_init(int* __restrict__ counts,
                                              float* __restrict__ csum,
                                              unsigned* __restrict__ done) {
  const int i = blockIdx.x * 256 + threadIdx.x;
  const int stride = gridDim.x * 256;
  if (i < NCLS) counts[i] = 0;
  if (i == 0) *done = 0u;
  for (int j = i; j < NCLS * DIM; j += stride) csum[j] = 0.f;
}

// ------------------------------------------------- class partial sums
__global__ __launch_bounds__(256) void k_class_sums(const float* __restrict__ x,
                                                    const int* __restrict__ y,
                                                    float* __restrict__ csum,
                                                    int* __restrict__ counts) {
  __shared__ int list[4096];
  __shared__ int lcnt;
  const int c  = blockIdx.x >> 4;
  const int r0 = (blockIdx.x & 15) * 4096;
  const int tid = threadIdx.x;
  if (tid == 0) lcnt = 0;
  __syncthreads();
  for (int i = tid; i < 4096; i += 256) {
    if (y[r0 + i] == c) { int p = atomicAdd(&lcnt, 1); list[p] = r0 + i; }
  }
  __syncthreads();
  const int n = lcnt;
  const int dbase = (tid >> 6) * 128 + (tid & 63) * 2;
  float a0 = 0.f, a1 = 0.f, b0 = 0.f, b1 = 0.f;
  int i = 0;
  for (; i + 2 <= n; i += 2) {
    const float* p0 = x + (size_t)list[i] * DIM + dbase;
    const float* p1 = x + (size_t)list[i + 1] * DIM + dbase;
    a0 += p0[0]; a1 += p0[1];
    b0 += p1[0]; b1 += p1[1];
  }
  if (i < n) { const float* p0 = x + (size_t)list[i] * DIM + dbase; a0 += p0[0]; a1 += p0[1]; }
  a0 += b0; a1 += b1;
  atomicAdd(&csum[c * DIM + dbase], a0);
  atomicAdd(&csum[c * DIM + dbase + 1], a1);
  if (tid == 0) atomicAdd(&counts[c], n);
}

// ------------------------------------------------- finalize centers (bf16) + c2 (f32)
__global__ __launch_bounds__(64) void k_centers(const float* __restrict__ csum,
                                                const int* __restrict__ counts,
                                                unsigned short* __restrict__ cenb,
                                                float* __restrict__ c2) {
  const int c = blockIdx.x, l = threadIdx.x;
  const float inv = 1.0f / (float)counts[c];
  float ss = 0.f;
  #pragma unroll
  for (int j = 0; j < 8; ++j) {
    int d = j * 64 + l;
    float v = csum[c * DIM + d] * inv;
    cenb[c * DIM + d] = f2bf_rne(v);
    ss += v * v;
  }
  #pragma unroll
  for (int o = 32; o; o >>= 1) ss += __shfl_down(ss, o, 64);
  if (l == 0) c2[c] = ss;
}

// ------------------------------------------------- distances via bf16 MFMA (unchanged, proven)
#define CSTR 520
__global__ __launch_bounds__(512, 4) void k_dist_mfma(const float* __restrict__ x,
                                                      const unsigned short* __restrict__ cenb,
                                                      const float* __restrict__ c2,
                                                      float* __restrict__ dist) {
  __shared__ unsigned short cenS[NCLS * CSTR];
  __shared__ float c2s[NCLS];

  const int tid = threadIdx.x;
  const int wave = tid >> 6;
  const int lane = tid & 63;
  const int s0 = blockIdx.x * 128 + wave * 16;
  const int samp = s0 + (lane & 15);
  const int kg = lane >> 4;

  for (int q = tid; q < 4096; q += 512) {
    const int row = q >> 6, cc = q & 63;
    const uint4 v = *reinterpret_cast<const uint4*>(cenb + row * DIM + cc * 8);
    *reinterpret_cast<uint4*>(&cenS[row * CSTR + cc * 8]) = v;
  }
  if (tid < NCLS) c2s[tid] = c2[tid];
  __syncthreads();

  f32x4 acc[4] = {f32x4{0,0,0,0}, f32x4{0,0,0,0}, f32x4{0,0,0,0}, f32x4{0,0,0,0}};
  float x2 = 0.f;
  const float* __restrict__ xrow = x + (size_t)samp * DIM + kg * 8;
  const int arow = lane & 15;

  #pragma unroll 4
  for (int s = 0; s < 16; ++s) {
    const int k0 = s * 32;
    float xf[8];
    *reinterpret_cast<float4*>(&xf[0]) = *reinterpret_cast<const float4*>(xrow + k0);
    *reinterpret_cast<float4*>(&xf[4]) = *reinterpret_cast<const float4*>(xrow + k0 + 4);
    bf16x8 bfrag;
    #pragma unroll
    for (int j = 0; j < 8; ++j) {
      x2 = fmaf(xf[j], xf[j], x2);
      const unsigned u = __float_as_uint(xf[j]);
      bfrag[j] = (short)((u + 0x7FFFu + ((u >> 16) & 1u)) >> 16);
    }
    const int kidx = k0 + kg * 8;
    const bf16x8 a0 = *reinterpret_cast<const bf16x8*>(&cenS[(arow +  0) * CSTR + kidx]);
    const bf16x8 a1 = *reinterpret_cast<const bf16x8*>(&cenS[(arow + 16) * CSTR + kidx]);
    const bf16x8 a2 = *reinterpret_cast<const bf16x8*>(&cenS[(arow + 32) * CSTR + kidx]);
    const bf16x8 a3 = *reinterpret_cast<const bf16x8*>(&cenS[(arow + 48) * CSTR + kidx]);
    acc[0] = __builtin_amdgcn_mfma_f32_16x16x32_bf16(a0, bfrag, acc[0], 0, 0, 0);
    acc[1] = __builtin_amdgcn_mfma_f32_16x16x32_bf16(a1, bfrag, acc[1], 0, 0, 0);
    acc[2] = __builtin_amdgcn_mfma_f32_16x16x32_bf16(a2, bfrag, acc[2], 0, 0, 0);
    acc[3] = __builtin_amdgcn_mfma_f32_16x16x32_bf16(a3, bfrag, acc[3], 0, 0, 0);
  }

  x2 += __shfl_xor(x2, 16, 64);
  x2 += __shfl_xor(x2, 32, 64);

  const int col = s0 + (lane & 15);
  #pragma unroll
  for (int t = 0; t < 4; ++t) {
    #pragma unroll
    for (int r = 0; r < 4; ++r) {
      const int cls = t * 16 + (lane >> 4) * 4 + r;
      const float d2 = c2s[cls] + x2 - 2.0f * acc[t][r];
      dist[(size_t)cls * N_SAMP + col] = sqrtf(fmaxf(d2, 1e-12f));
    }
  }
}

// ------------------------------------------------- block reduce: {sum,sum,min,max,sum,sum}
__device__ __forceinline__ void redSix(float v0, float v1, float v2, float v3, float v4, float v5,
                                       float* redf, float* bcast) {
  #pragma unroll
  for (int o = 32; o; o >>= 1) {
    v0 += __shfl_xor(v0, o, 64);
    v1 += __shfl_xor(v1, o, 64);
    v2 = fminf(v2, __shfl_xor(v2, o, 64));
    v3 = fmaxf(v3, __shfl_xor(v3, o, 64));
    v4 += __shfl_xor(v4, o, 64);
    v5 += __shfl_xor(v5, o, 64);
  }
  const int wid = threadIdx.x >> 6;
  if ((threadIdx.x & 63) == 0) {
    redf[wid] = v0; redf[16 + wid] = v1; redf[32 + wid] = v2;
    redf[48 + wid] = v3; redf[64 + wid] = v4; redf[80 + wid] = v5;
  }
  __syncthreads();
  if (threadIdx.x < 16) {
    const int l = threadIdx.x;
    float a0 = redf[l], a1 = redf[16 + l], a2 = redf[32 + l],
          a3 = redf[48 + l], a4 = redf[64 + l], a5 = redf[80 + l];
    #pragma unroll
    for (int o = 8; o; o >>= 1) {
      a0 += __shfl_xor(a0, o, 64);
      a1 += __shfl_xor(a1, o, 64);
      a2 = fminf(a2, __shfl_xor(a2, o, 64));
      a3 = fmaxf(a3, __shfl_xor(a3, o, 64));
      a4 += __shfl_xor(a4, o, 64);
      a5 += __shfl_xor(a5, o, 64);
    }
    if (l == 0) { bcast[0]=a0; bcast[1]=a1; bcast[2]=a2; bcast[3]=a3; bcast[4]=a4; bcast[5]=a5; }
  }
  __syncthreads();
}

// ------------------------------------------------- single-shot selection + fused loss
// grid 128: c = bx>>1, neg = bx&1. One adaptive hist + one scan + exact boundary.
__global__ __launch_bounds__(1024, 4) void k_select2(const float* __restrict__ dist,
                                                     const int* __restrict__ y,
                                                     float* __restrict__ means,
                                                     unsigned* __restrict__ done,
                                                     float* __restrict__ out) {
  __shared__ unsigned bitmap[2048];
  __shared__ unsigned hist[1024];
  __shared__ unsigned wscan[16];
  __shared__ float redf[96];
  __shared__ float bcast[8];
  __shared__ float bbuf[1024];
  __shared__ int bcnt_s;
  __shared__ int bsel;
  __shared__ int lastflag;

  const int tid = threadIdx.x;
  const int c = blockIdx.x >> 1;
  const int neg = blockIdx.x & 1;
  const float* __restrict__ row = dist + (size_t)c * N_SAMP;

  if (tid == 0) { bcnt_s = 0; bsel = 1023; lastflag = 0; }

  #pragma unroll
  for (int j = 0; j < 2; ++j) {
    unsigned wbits = 0u;
    const int base = tid * 64 + j * 32;
    #pragma unroll
    for (int b = 0; b < 32; ++b) wbits |= (unsigned)(y[base + b] == c) << b;
    bitmap[tid * 2 + j] = wbits;
  }
  __syncthreads();

  const float qnan = __uint_as_float(0x7fc00000u);
  float vals[64];
  float mn = 1e30f, mx = -1e30f;
  #pragma unroll
  for (int i = 0; i < 64; ++i) {
    const int n = i * 1024 + tid;
    const unsigned bit = (bitmap[n >> 5] >> (n & 31)) & 1u;
    float v = row[n];
    if (!neg) v = -v;                          // pos: largest dist == smallest -dist
    const float vv = ((int)bit != neg) ? v : qnan;
    vals[i] = vv;
    mn = fminf(mn, vv);
    mx = fmaxf(mx, vv);
  }
  redSix(0.f, 0.f, mn, mx, 0.f, 0.f, redf, bcast);
  const float lo = bcast[2], hi = bcast[3];

  float meanval;
  if (!(hi > lo)) {                            // degenerate: all candidates equal
    meanval = neg ? lo : -lo;
  } else {
    const float scale = 1024.0f / (hi - lo);
    hist[tid] = 0u;
    __syncthreads();
    #pragma unroll
    for (int i = 0; i < 64; ++i) {
      const float v = vals[i];
      if (v >= lo && v <= hi) {
        int b = (int)((v - lo) * scale);
        b = b < 1023 ? b : 1023; b = b > 0 ? b : 0;
        atomicAdd(&hist[b], 1u);
      }
    }
    __syncthreads();
    // 2-level inclusive scan over 1024 bins
    const int lane = tid & 63, wid = tid >> 6;
    const unsigned h = hist[tid];
    unsigned cum = h;
    #pragma unroll
    for (int d = 1; d < 64; d <<= 1) {
      const unsigned t = (unsigned)__shfl_up((int)cum, d, 64);
      if (lane >= d) cum += t;
    }
    if (lane == 63) wscan[wid] = cum;
    __syncthreads();
    if (tid < 16) {
      unsigned v = wscan[tid];
      #pragma unroll
      for (int d = 1; d < 16; d <<= 1) {
        const unsigned t = (unsigned)__shfl_up((int)v, d, 64);
        if (tid >= d) v += t;
      }
      wscan[tid] = v;
    }
    __syncthreads();
    const unsigned full = cum + (wid ? wscan[wid - 1] : 0u);
    hist[tid] = full;                          // now holds inclusive scan
    const unsigned prev = full - h;
    if (full >= (unsigned)KSEL && prev < (unsigned)KSEL) bsel = tid;
    __syncthreads();
    const int B = bsel;
    const unsigned SC = B ? hist[B - 1] : 0u;  // strict count (< KSEL)
    const int need = KSEL - (int)SC;

    // strict sum + boundary collection (exact)
    float ss = 0.f;
    #pragma unroll
    for (int i = 0; i < 64; ++i) {
      const float v = vals[i];
      if (v >= lo && v <= hi) {
        int b = (int)((v - lo) * scale);
        b = b < 1023 ? b : 1023; b = b > 0 ? b : 0;
        if (b < B) ss += v;
        else if (b == B) {
          const int p = atomicAdd(&bcnt_s, 1);
          if (p < 1024) bbuf[p] = v;
        }
      }
    }
    redSix(ss, 0.f, 0.f, 0.f, 0.f, 0.f, redf, bcast);
    const float SS = bcast[0];
    const int cnt = bcnt_s;                    // final after redSix barriers
    float bsum = 0.f;

    if (cnt <= 1024) {
      const int L = (cnt <= 256) ? 256 : 1024;
      if (tid < L) bbuf[tid] = (tid < cnt) ? bbuf[tid] : __uint_as_float(0x7F800000u);
      __syncthreads();
      for (int k = 2; k <= L; k <<= 1) {
        for (int j = k >> 1; j > 0; j >>= 1) {
          const int ixj = tid ^ j;
          float a = 0.f, b2 = 0.f;
          if (tid < L) { a = bbuf[tid]; b2 = bbuf[ixj]; }
          __syncthreads();
          if (tid < L && ixj > tid) {
            const bool asc = ((tid & k) == 0);
            if ((a > b2) == asc) { bbuf[tid] = b2; bbuf[ixj] = a; }
          }
          __syncthreads();
        }
      }
      float v = (tid < need) ? bbuf[tid] : 0.f;  // smallest `need` in signed domain
      redSix(v, 0.f, 0.f, 0.f, 0.f, 0.f, redf, bcast);
      bsum = bcast[0];
    } else {
      // exact min-peel fallback among bin-B values (practically unreachable)
      float thr = -1e30f;
      int rem2 = need;
      for (int g = 0; g < 64 && rem2 > 0; ++g) {
        float m = 1e30f;
        #pragma unroll
        for (int i = 0; i < 64; ++i) {
          const float v = vals[i];
          if (v >= lo && v <= hi) {
            int b = (int)((v - lo) * scale);
            b = b < 1023 ? b : 1023; b = b > 0 ? b : 0;
            if (b == B && v > thr) m = fminf(m, v);
          }
        }
        redSix(0.f, 0.f, m, 0.f, 0.f, 0.f, redf, bcast);
        const float M = bcast[2];
        float ce = 0.f;
        #pragma unroll
        for (int i = 0; i < 64; ++i) {
          const float v = vals[i];
          if (v >= lo && v <= hi) {
            int b = (int)((v - lo) * scale);
            b = b < 1023 ? b : 1023; b = b > 0 ? b : 0;
            if (b == B && v == M) ce += 1.f;
          }
        }
        redSix(0.f, 0.f, 0.f, 0.f, ce, 0.f, redf, bcast);
        const int CE = (int)bcast[4];
        const int take = rem2 < CE ? rem2 : CE;
        bsum += (float)take * M;
        rem2 -= take;
        thr = M;
      }
    }
    const float total = SS + bsum;
    meanval = neg ? total * (1.0f / 64.0f) : -total * (1.0f / 64.0f);
  }

  // publish mean; last block computes loss
  if (tid == 0) {
    __hip_atomic_store(&means[neg * 64 + c], meanval, __ATOMIC_RELAXED, __HIP_MEMORY_SCOPE_AGENT);
    const unsigned old = __hip_atomic_fetch_add(done, 1u, __ATOMIC_ACQ_REL, __HIP_MEMORY_SCOPE_AGENT);
    lastflag = (old == 127u) ? 1 : 0;
  }
  __syncthreads();
  if (lastflag && tid < 64) {
    const float pm = __hip_atomic_load(&means[tid], __ATOMIC_ACQUIRE, __HIP_MEMORY_SCOPE_AGENT);
    const float nm = __hip_atomic_load(&means[64 + tid], __ATOMIC_ACQUIRE, __HIP_MEMORY_SCOPE_AGENT);
    float pc = fmaxf(1.0f + pm - nm, 0.0f);
    #pragma unroll
    for (int o = 32; o; o >>= 1) pc += __shfl_down(pc, o, 64);
    if (tid == 0) out[0] = pc * (1.0f / 4096.0f);
  }
}

// ----------------------------------------------------------------------
extern "C" void kernel_launch(void* const* d_in, const int* in_sizes, int n_in,
                              void* d_out, int out_size, void* d_ws, size_t ws_size,
                              hipStream_t stream) {
  const float* x = (const float*)d_in[0];
  const int* y = (const int*)d_in[1];
  float* out = (float*)d_out;
  char* w = (char*)d_ws;
  int* counts          = (int*)(w + OFF_COUNTS);
  float* csum          = (float*)(w + OFF_CSUM);
  unsigned short* cenb = (unsigned short*)(w + OFF_CENTERS);
  float* c2            = (float*)(w + OFF_C2);
  float* means         = (float*)(w + OFF_MEANS);
  unsigned* done       = (unsigned*)(w + OFF_DONE);
  float* dist          = (float*)(w + OFF_DIST);

  hipLaunchKernelGGL(k_init, dim3(64), dim3(256), 0, stream, counts, csum, done);
  hipLaunchKernelGGL(k_class_sums, dim3(1024), dim3(256), 0, stream, x, y, csum, counts);
  hipLaunchKernelGGL(k_centers, dim3(64), dim3(64), 0, stream, csum, counts, cenb, c2);
  hipLaunchKernelGGL(k_dist_mfma, dim3(N_SAMP / 128), dim3(512), 0, stream, x, cenb, c2, dist);
  hipLaunchKernelGGL(k_select2, dim3(128), dim3(1024), 0, stream, dist, y, means, done, out);
}